// Round 4
// baseline (316.785 us; speedup 1.0000x reference)
//
#include <hip/hip_runtime.h>

#define N_NODES 50000
#define N_EDGES 800000
#define D 128
#define NCHUNK 196            // ceil(50000/256)
#define NPLANES 8
#define PLANE_COLS 16         // 128/8 cols per plane
#define PLANE_STRIDE 800000   // floats per plane = 50000*16 (3.2 MB, fits 4 MiB per-XCD L2)
#define DST_BUCKET 6250       // 50000/8 dst nodes per XCD bucket

typedef float f32x4 __attribute__((ext_vector_type(4)));

// ---------- graph build ----------

__global__ void k_zero(int* __restrict__ p, int n) {
    int i = blockIdx.x * blockDim.x + threadIdx.x;
    if (i < n) p[i] = 0;
}

__global__ void k_hist(const int* __restrict__ ei, int* __restrict__ cnt) {
    int e = blockIdx.x * blockDim.x + threadIdx.x;
    if (e < N_EDGES) atomicAdd(&cnt[ei[N_EDGES + e]], 1);
}

__global__ void k_scan1(const int* __restrict__ cnt, int* __restrict__ chunkscan,
                        int* __restrict__ csum) {
    __shared__ int sd[256];
    int t = threadIdx.x;
    int i = blockIdx.x * 256 + t;
    int v = (i < N_NODES) ? cnt[i] : 0;
    sd[t] = v;
    __syncthreads();
    for (int off = 1; off < 256; off <<= 1) {
        int u = (t >= off) ? sd[t - off] : 0;
        __syncthreads();
        sd[t] += u;
        __syncthreads();
    }
    if (i < N_NODES) chunkscan[i] = sd[t] - v;   // exclusive within chunk
    if (t == 255) csum[blockIdx.x] = sd[255];    // chunk total
}

__global__ void k_scan2(int* __restrict__ csum, int nb) {
    __shared__ int sd[256];
    int t = threadIdx.x;
    int v = (t < nb) ? csum[t] : 0;
    sd[t] = v;
    __syncthreads();
    for (int off = 1; off < 256; off <<= 1) {
        int u = (t >= off) ? sd[t - off] : 0;
        __syncthreads();
        sd[t] += u;
        __syncthreads();
    }
    if (t < nb) csum[t] = sd[t] - v;             // exclusive scan of chunk totals
}

__global__ void k_finalize(const int* __restrict__ cnt, const int* __restrict__ chunkscan,
                           const int* __restrict__ csum, int* __restrict__ rowptr,
                           int* __restrict__ cursor, float* __restrict__ dinv) {
    int i = blockIdx.x * 256 + threadIdx.x;
    if (i < N_NODES) {
        int r = chunkscan[i] + csum[i >> 8];
        rowptr[i] = r;
        cursor[i] = r;
        dinv[i] = rsqrtf((float)cnt[i] + 1.0f);  // +1 self-loop
    }
    if (i == 0) rowptr[N_NODES] = N_EDGES;
}

// dst-bucket-partitioned CSR scatter: block b handles dst in [6250*(b&7), +6250),
// so cursor atomics + esrc writes stay in that XCD's L2 (bid%8 -> XCD round-robin).
// dst column is re-read 8x (streamed, NT); write RMW amplification eliminated.
__global__ void k_scatter(const int* __restrict__ ei, int* __restrict__ cursor,
                          int* __restrict__ esrc) {
    const int p = blockIdx.x & 7;
    int e = (blockIdx.x >> 3) * 256 + threadIdx.x;   // grid/8*256 == N_EDGES exactly
    const int lo = p * DST_BUCKET, hi = lo + DST_BUCKET;
    int dt = __builtin_nontemporal_load(&ei[N_EDGES + e]);
    if (dt >= lo && dt < hi) {
        int s = ei[e];
        int pos = atomicAdd(&cursor[dt], 1);
        esrc[pos] = s;
    }
}

// ---------- dense transform: H' = (X @ W) * dinv[row], stored PLANE-MAJOR ----------
// H'[plane p][node n][16 floats], p = col/16. 64 rows/block, T_M=8 register tile.

__global__ __launch_bounds__(256) void k_gemm(const float* __restrict__ X,
                                              const float* __restrict__ W,
                                              const float* __restrict__ dinv,
                                              float* __restrict__ H) {
    __shared__ f32x4 Ws[64 * 32];   // 32 KiB: half of W, [kk][j4]
    __shared__ float Xt[128][64];   // 32 KiB: transposed X tile [k][row]

    const int tid  = threadIdx.x;
    const int base = blockIdx.x * 64;

    {
        int r  = tid >> 2;
        int gr = base + r;
        if (gr >= N_NODES) gr = N_NODES - 1;      // clamp; tail rows never stored
        const f32x4* Xr = (const f32x4*)(X + (size_t)gr * D);
#pragma unroll
        for (int j = 0; j < 8; ++j) {
            int c = (tid & 3) + 4 * j;
            f32x4 v = Xr[c];
            int k0 = c * 4;
            Xt[k0 + 0][r] = v.x;
            Xt[k0 + 1][r] = v.y;
            Xt[k0 + 2][r] = v.z;
            Xt[k0 + 3][r] = v.w;
        }
    }

    const int rg = tid >> 5;
    const int c4 = tid & 31;
    f32x4 acc[8];
#pragma unroll
    for (int j = 0; j < 8; ++j) acc[j] = (f32x4)0.f;

    const f32x4* Wv = (const f32x4*)W;
#pragma unroll
    for (int h = 0; h < 2; ++h) {
        __syncthreads();             // Xt ready (h=0) / prev W half consumed (h=1)
        for (int i = tid; i < 64 * 32; i += 256) Ws[i] = Wv[h * 2048 + i];
        __syncthreads();
#pragma unroll 4
        for (int kk = 0; kk < 64; ++kk) {
            f32x4 w  = Ws[kk * 32 + c4];
            f32x4 xa = *(const f32x4*)&Xt[h * 64 + kk][rg * 8];
            f32x4 xb = *(const f32x4*)&Xt[h * 64 + kk][rg * 8 + 4];
#pragma unroll
            for (int j = 0; j < 4; ++j) acc[j]     += w * xa[j];
#pragma unroll
            for (int j = 0; j < 4; ++j) acc[j + 4] += w * xb[j];
        }
    }

    // epilogue: scale by dinv[row], store plane-major (plane = c4>>2, sub = c4&3)
#pragma unroll
    for (int j = 0; j < 8; ++j) {
        int gr = base + rg * 8 + j;
        if (gr < N_NODES) {
            float s = dinv[gr];
            f32x4 r = acc[j] * s;
            f32x4* dst = (f32x4*)(H + (size_t)(c4 >> 2) * PLANE_STRIDE + (size_t)gr * PLANE_COLS)
                         + (c4 & 3);
            __builtin_nontemporal_store(r, dst);
        }
    }
}

// ---------- aggregation: out[n] = dinv[n]*(h'[n] + sum_e h'[src]) + b ----------
// Plane-partitioned: block b works on feature plane (b&7) only -> that XCD's L2
// holds the whole 3.2 MB plane. 4-lane groups (one node each, 16 cols), CSR gather.
// esrc/rowptr/dinv loads are nontemporal so streams don't evict the plane.

template <int RELU>
__global__ __launch_bounds__(256) void k_agg(const float* __restrict__ Hs,
                                             const int* __restrict__ esrc,
                                             const int* __restrict__ rowptr,
                                             const float* __restrict__ dinv,
                                             const float* __restrict__ bias,
                                             float* __restrict__ OUT) {
    const int plane = blockIdx.x & 7;
    const int lane4 = threadIdx.x & 3;
    const int node  = (blockIdx.x >> 3) * 64 + (threadIdx.x >> 2);
    if (node >= N_NODES) return;                 // group-uniform

    const f32x4* HP = (const f32x4*)Hs + (size_t)plane * (PLANE_STRIDE / 4);

    f32x4 acc = HP[(size_t)node * 4 + lane4];    // h'[n] (self-loop term)

    int s = __builtin_nontemporal_load(&rowptr[node]);
    int e = __builtin_nontemporal_load(&rowptr[node + 1]);
    int off = s;
#pragma unroll 2
    for (; off + 4 <= e; off += 4) {
        int eidx = __builtin_nontemporal_load(&esrc[off + lane4]);
        int s0 = __shfl(eidx, 0, 4);
        int s1 = __shfl(eidx, 1, 4);
        int s2 = __shfl(eidx, 2, 4);
        int s3 = __shfl(eidx, 3, 4);
        f32x4 v0 = HP[(size_t)s0 * 4 + lane4];
        f32x4 v1 = HP[(size_t)s1 * 4 + lane4];
        f32x4 v2 = HP[(size_t)s2 * 4 + lane4];
        f32x4 v3 = HP[(size_t)s3 * 4 + lane4];
        acc += (v0 + v1) + (v2 + v3);
    }
    int rem = e - off;
    if (rem > 0) {
        int idx = off + (lane4 < rem ? lane4 : rem - 1);
        int eidx = __builtin_nontemporal_load(&esrc[idx]);
        for (int j = 0; j < rem; ++j) {
            int sj = __shfl(eidx, j, 4);
            acc += HP[(size_t)sj * 4 + lane4];
        }
    }

    float di = __builtin_nontemporal_load(&dinv[node]);
    f32x4 b = ((const f32x4*)bias)[plane * 4 + lane4];
    f32x4 r = acc * di + b;
    if (RELU) {
        r.x = fmaxf(r.x, 0.f);
        r.y = fmaxf(r.y, 0.f);
        r.z = fmaxf(r.z, 0.f);
        r.w = fmaxf(r.w, 0.f);
    }
    // row-major output: out[node][plane*16 + lane4*4 .. +4]; 64B/group NT store
    __builtin_nontemporal_store(r, (f32x4*)OUT + (size_t)node * 32 + plane * 4 + lane4);
}

// ---------- launch ----------

extern "C" void kernel_launch(void* const* d_in, const int* in_sizes, int n_in,
                              void* d_out, int out_size, void* d_ws, size_t ws_size,
                              hipStream_t stream) {
    const float* x  = (const float*)d_in[0];
    const int*   ei = (const int*)d_in[1];
    const float* W1 = (const float*)d_in[2];
    const float* b1 = (const float*)d_in[3];
    const float* W2 = (const float*)d_in[4];
    const float* b2 = (const float*)d_in[5];
    float* out = (float*)d_out;

    // ws layout (elements, 4B each; chunks padded to keep 16B alignment)
    int*   cnt       = (int*)d_ws;               // 50000
    int*   chunkscan = cnt + 50048;              // 50000
    int*   csum      = chunkscan + 50048;        // 256
    int*   rowptr    = csum + 256;               // 50001
    int*   cursor    = rowptr + 50048;           // 50000
    float* dinv      = (float*)(cursor + 50048); // 50000
    int*   esrc      = (int*)(dinv + 50048);     // 800000
    float* h         = (float*)(esrc + 800000);  // 6,400,000 (plane-major)
    float* agg       = h + 6400000;              // 6,400,000 (row-major)

    const int TB = 256;
    const int gbN = (N_NODES + TB - 1) / TB;     // 196
    const int gbE = (N_EDGES + TB - 1) / TB;     // 3125
    const int gbG = (N_NODES + 63) / 64;         // 782 gemm blocks
    const int gbA = 8 * ((N_NODES + 63) / 64);   // 6256 agg blocks (8 planes)

    // graph build (shared by both layers)
    k_zero<<<gbN, TB, 0, stream>>>(cnt, N_NODES);
    k_hist<<<gbE, TB, 0, stream>>>(ei, cnt);
    k_scan1<<<NCHUNK, TB, 0, stream>>>(cnt, chunkscan, csum);
    k_scan2<<<1, TB, 0, stream>>>(csum, NCHUNK);
    k_finalize<<<gbN, TB, 0, stream>>>(cnt, chunkscan, csum, rowptr, cursor, dinv);
    k_scatter<<<8 * gbE, TB, 0, stream>>>(ei, cursor, esrc);

    // layer 1
    k_gemm<<<gbG, TB, 0, stream>>>(x, W1, dinv, h);
    k_agg<1><<<gbA, TB, 0, stream>>>(h, esrc, rowptr, dinv, b1, agg);
    // layer 2
    k_gemm<<<gbG, TB, 0, stream>>>(agg, W2, dinv, h);
    k_agg<0><<<gbA, TB, 0, stream>>>(h, esrc, rowptr, dinv, b2, out);
}

// Round 5
// 215.342 us; speedup vs baseline: 1.4711x; 1.4711x over previous
//
#include <hip/hip_runtime.h>

#define N_NODES 50000
#define N_EDGES 800000
#define D 128
#define NCHUNK 196            // ceil(50000/256)
#define DST_BUCKET 6250       // 50000/8 dst nodes per XCD bucket

typedef float    f32x4 __attribute__((ext_vector_type(4)));
typedef _Float16 f16x4 __attribute__((ext_vector_type(4)));

__device__ inline f32x4 cvt4(f16x4 h) {
    f32x4 r;
    r.x = (float)h.x; r.y = (float)h.y; r.z = (float)h.z; r.w = (float)h.w;
    return r;
}

// ---------- graph build ----------

__global__ void k_zero(int* __restrict__ p, int n) {
    int i = blockIdx.x * blockDim.x + threadIdx.x;
    if (i < n) p[i] = 0;
}

__global__ void k_hist(const int* __restrict__ ei, int* __restrict__ cnt) {
    int e = blockIdx.x * blockDim.x + threadIdx.x;
    if (e < N_EDGES) atomicAdd(&cnt[ei[N_EDGES + e]], 1);
}

__global__ void k_scan1(const int* __restrict__ cnt, int* __restrict__ chunkscan,
                        int* __restrict__ csum) {
    __shared__ int sd[256];
    int t = threadIdx.x;
    int i = blockIdx.x * 256 + t;
    int v = (i < N_NODES) ? cnt[i] : 0;
    sd[t] = v;
    __syncthreads();
    for (int off = 1; off < 256; off <<= 1) {
        int u = (t >= off) ? sd[t - off] : 0;
        __syncthreads();
        sd[t] += u;
        __syncthreads();
    }
    if (i < N_NODES) chunkscan[i] = sd[t] - v;   // exclusive within chunk
    if (t == 255) csum[blockIdx.x] = sd[255];    // chunk total
}

__global__ void k_scan2(int* __restrict__ csum, int nb) {
    __shared__ int sd[256];
    int t = threadIdx.x;
    int v = (t < nb) ? csum[t] : 0;
    sd[t] = v;
    __syncthreads();
    for (int off = 1; off < 256; off <<= 1) {
        int u = (t >= off) ? sd[t - off] : 0;
        __syncthreads();
        sd[t] += u;
        __syncthreads();
    }
    if (t < nb) csum[t] = sd[t] - v;             // exclusive scan of chunk totals
}

__global__ void k_finalize(const int* __restrict__ cnt, const int* __restrict__ chunkscan,
                           const int* __restrict__ csum, int* __restrict__ rowptr,
                           int* __restrict__ cursor, float* __restrict__ dinv) {
    int i = blockIdx.x * 256 + threadIdx.x;
    if (i < N_NODES) {
        int r = chunkscan[i] + csum[i >> 8];
        rowptr[i] = r;
        cursor[i] = r;
        dinv[i] = rsqrtf((float)cnt[i] + 1.0f);  // +1 self-loop
    }
    if (i == 0) rowptr[N_NODES] = N_EDGES;
}

// dst-bucket-partitioned CSR scatter: block b handles dst in [6250*(b&7), +6250),
// so cursor atomics + esrc writes stay in that XCD's L2 (bid%8 -> XCD round-robin).
__global__ void k_scatter(const int* __restrict__ ei, int* __restrict__ cursor,
                          int* __restrict__ esrc) {
    const int p = blockIdx.x & 7;
    int e = (blockIdx.x >> 3) * 256 + threadIdx.x;   // grid/8*256 == N_EDGES exactly
    const int lo = p * DST_BUCKET, hi = lo + DST_BUCKET;
    int dt = __builtin_nontemporal_load(&ei[N_EDGES + e]);
    if (dt >= lo && dt < hi) {
        int s = ei[e];
        int pos = atomicAdd(&cursor[dt], 1);
        esrc[pos] = s;
    }
}

// ---------- dense transform: H' = fp16( (X @ W) * dinv[row] ), row-major ----------
// 64 rows/block, 256 threads, T_M=8 register tile. fp16 output halves the gather
// working set (12.8 MB) and bytes/edge for k_agg.

__global__ __launch_bounds__(256) void k_gemm(const float* __restrict__ X,
                                              const float* __restrict__ W,
                                              const float* __restrict__ dinv,
                                              _Float16* __restrict__ H) {
    __shared__ f32x4 Ws[64 * 32];   // 32 KiB: half of W, [kk][j4]
    __shared__ float Xt[128][64];   // 32 KiB: transposed X tile [k][row]

    const int tid  = threadIdx.x;
    const int base = blockIdx.x * 64;

    {
        int r  = tid >> 2;
        int gr = base + r;
        if (gr >= N_NODES) gr = N_NODES - 1;      // clamp; tail rows never stored
        const f32x4* Xr = (const f32x4*)(X + (size_t)gr * D);
#pragma unroll
        for (int j = 0; j < 8; ++j) {
            int c = (tid & 3) + 4 * j;
            f32x4 v = Xr[c];
            int k0 = c * 4;
            Xt[k0 + 0][r] = v.x;
            Xt[k0 + 1][r] = v.y;
            Xt[k0 + 2][r] = v.z;
            Xt[k0 + 3][r] = v.w;
        }
    }

    const int rg = tid >> 5;
    const int c4 = tid & 31;
    f32x4 acc[8];
#pragma unroll
    for (int j = 0; j < 8; ++j) acc[j] = (f32x4)0.f;

    const f32x4* Wv = (const f32x4*)W;
#pragma unroll
    for (int h = 0; h < 2; ++h) {
        __syncthreads();             // Xt ready (h=0) / prev W half consumed (h=1)
        for (int i = tid; i < 64 * 32; i += 256) Ws[i] = Wv[h * 2048 + i];
        __syncthreads();
#pragma unroll 4
        for (int kk = 0; kk < 64; ++kk) {
            f32x4 w  = Ws[kk * 32 + c4];
            f32x4 xa = *(const f32x4*)&Xt[h * 64 + kk][rg * 8];
            f32x4 xb = *(const f32x4*)&Xt[h * 64 + kk][rg * 8 + 4];
#pragma unroll
            for (int j = 0; j < 4; ++j) acc[j]     += w * xa[j];
#pragma unroll
            for (int j = 0; j < 4; ++j) acc[j + 4] += w * xb[j];
        }
    }

#pragma unroll
    for (int j = 0; j < 8; ++j) {
        int gr = base + rg * 8 + j;
        if (gr < N_NODES) {
            float s = dinv[gr];
            f32x4 r = acc[j] * s;
            f16x4 hv;
            hv.x = (_Float16)r.x; hv.y = (_Float16)r.y;
            hv.z = (_Float16)r.z; hv.w = (_Float16)r.w;
            ((f16x4*)(H + (size_t)gr * D))[c4] = hv;
        }
    }
}

// ---------- aggregation: out[n] = dinv[n]*(h'[n] + sum_e h'[src]) + b ----------
// 32 lanes per node (f16x4 = 8 B/lane, 256 B/row = 4 cache lines per edge).
// One coalesced 32-wide load fetches 32 edge indices; __shfl broadcasts give 4
// independent row-gathers in flight. f32 accumulation after fp16 convert.

template <int RELU>
__global__ __launch_bounds__(256) void k_agg(const _Float16* __restrict__ Hs,
                                             const int* __restrict__ esrc,
                                             const int* __restrict__ rowptr,
                                             const float* __restrict__ dinv,
                                             const float* __restrict__ bias,
                                             float* __restrict__ OUT) {
    int node = blockIdx.x * 8 + (threadIdx.x >> 5);
    int lane = threadIdx.x & 31;
    const f16x4* Hv = (const f16x4*)Hs;

    float di = dinv[node];
    f32x4 acc = cvt4(Hv[(size_t)node * 32 + lane]);   // h'[n] (self-loop term)

    int s = rowptr[node], e = rowptr[node + 1];
    for (int off = s; off < e; off += 32) {
        int n = e - off;
        if (n > 32) n = 32;
        int idx  = off + (lane < n ? lane : n - 1);   // clamp: no OOB reads
        int eidx = __builtin_nontemporal_load(&esrc[idx]);
        int j = 0;
        for (; j + 3 < n; j += 4) {
            int s0 = __shfl(eidx, j, 32);
            int s1 = __shfl(eidx, j + 1, 32);
            int s2 = __shfl(eidx, j + 2, 32);
            int s3 = __shfl(eidx, j + 3, 32);
            f16x4 v0 = Hv[(size_t)s0 * 32 + lane];
            f16x4 v1 = Hv[(size_t)s1 * 32 + lane];
            f16x4 v2 = Hv[(size_t)s2 * 32 + lane];
            f16x4 v3 = Hv[(size_t)s3 * 32 + lane];
            acc += (cvt4(v0) + cvt4(v1)) + (cvt4(v2) + cvt4(v3));
        }
        for (; j < n; ++j) {
            int s0 = __shfl(eidx, j, 32);
            acc += cvt4(Hv[(size_t)s0 * 32 + lane]);
        }
    }

    f32x4 b = ((const f32x4*)bias)[lane];
    f32x4 r = acc * di + b;
    if (RELU) {
        r.x = fmaxf(r.x, 0.f);
        r.y = fmaxf(r.y, 0.f);
        r.z = fmaxf(r.z, 0.f);
        r.w = fmaxf(r.w, 0.f);
    }
    __builtin_nontemporal_store(r, (f32x4*)OUT + (size_t)node * 32 + lane);
}

// ---------- launch ----------

extern "C" void kernel_launch(void* const* d_in, const int* in_sizes, int n_in,
                              void* d_out, int out_size, void* d_ws, size_t ws_size,
                              hipStream_t stream) {
    const float* x  = (const float*)d_in[0];
    const int*   ei = (const int*)d_in[1];
    const float* W1 = (const float*)d_in[2];
    const float* b1 = (const float*)d_in[3];
    const float* W2 = (const float*)d_in[4];
    const float* b2 = (const float*)d_in[5];
    float* out = (float*)d_out;

    // ws layout (elements, 4B each; chunks padded to keep 16B alignment)
    int*      cnt       = (int*)d_ws;               // 50000
    int*      chunkscan = cnt + 50048;              // 50000
    int*      csum      = chunkscan + 50048;        // 256
    int*      rowptr    = csum + 256;               // 50001
    int*      cursor    = rowptr + 50048;           // 50000
    float*    dinv      = (float*)(cursor + 50048); // 50000
    int*      esrc      = (int*)(dinv + 50048);     // 800000
    _Float16* h         = (_Float16*)(esrc + 800000); // 6.4M halves (12.8 MB)
    float*    agg       = (float*)(esrc + 800000) + 3200000; // 6.4M floats

    const int TB = 256;
    const int gbN = (N_NODES + TB - 1) / TB;     // 196
    const int gbE = (N_EDGES + TB - 1) / TB;     // 3125
    const int gbG = (N_NODES + 63) / 64;         // 782 gemm blocks

    // graph build (shared by both layers)
    k_zero<<<gbN, TB, 0, stream>>>(cnt, N_NODES);
    k_hist<<<gbE, TB, 0, stream>>>(ei, cnt);
    k_scan1<<<NCHUNK, TB, 0, stream>>>(cnt, chunkscan, csum);
    k_scan2<<<1, TB, 0, stream>>>(csum, NCHUNK);
    k_finalize<<<gbN, TB, 0, stream>>>(cnt, chunkscan, csum, rowptr, cursor, dinv);
    k_scatter<<<8 * gbE, TB, 0, stream>>>(ei, cursor, esrc);

    // layer 1
    k_gemm<<<gbG, TB, 0, stream>>>(x, W1, dinv, h);
    k_agg<1><<<N_NODES / 8, TB, 0, stream>>>(h, esrc, rowptr, dinv, b1, agg);
    // layer 2
    k_gemm<<<gbG, TB, 0, stream>>>(agg, W2, dinv, h);
    k_agg<0><<<N_NODES / 8, TB, 0, stream>>>(h, esrc, rowptr, dinv, b2, out);
}

// Round 6
// 178.146 us; speedup vs baseline: 1.7782x; 1.2088x over previous
//
#include <hip/hip_runtime.h>

#define N_NODES 50000
#define N_EDGES 800000
#define D 128
#define NCHUNK 196            // ceil(50000/256)
#define DST_BUCKET 6250       // 50000/8 dst nodes per XCD bucket
#define WT_LD 136             // 128 + 8 fp16 pad (272B row stride, bank-spread)

typedef float    f32x4 __attribute__((ext_vector_type(4)));
typedef _Float16 f16x4 __attribute__((ext_vector_type(4)));
typedef _Float16 half8 __attribute__((ext_vector_type(8)));

__device__ inline f32x4 cvt4(f16x4 h) {
    f32x4 r;
    r.x = (float)h.x; r.y = (float)h.y; r.z = (float)h.z; r.w = (float)h.w;
    return r;
}

__device__ inline half8 cvt8(const float* __restrict__ p) {
    f32x4 a = *(const f32x4*)p;
    f32x4 b = *(const f32x4*)(p + 4);
    half8 r;
    r[0] = (_Float16)a.x; r[1] = (_Float16)a.y; r[2] = (_Float16)a.z; r[3] = (_Float16)a.w;
    r[4] = (_Float16)b.x; r[5] = (_Float16)b.y; r[6] = (_Float16)b.z; r[7] = (_Float16)b.w;
    return r;
}

// ---------- graph build ----------

__global__ void k_zero(int* __restrict__ p, int n) {
    int i = blockIdx.x * blockDim.x + threadIdx.x;
    if (i < n) p[i] = 0;
}

__global__ void k_hist(const int* __restrict__ ei, int* __restrict__ cnt) {
    int e = blockIdx.x * blockDim.x + threadIdx.x;
    if (e < N_EDGES) atomicAdd(&cnt[ei[N_EDGES + e]], 1);
}

__global__ void k_scan1(const int* __restrict__ cnt, int* __restrict__ chunkscan,
                        int* __restrict__ csum) {
    __shared__ int sd[256];
    int t = threadIdx.x;
    int i = blockIdx.x * 256 + t;
    int v = (i < N_NODES) ? cnt[i] : 0;
    sd[t] = v;
    __syncthreads();
    for (int off = 1; off < 256; off <<= 1) {
        int u = (t >= off) ? sd[t - off] : 0;
        __syncthreads();
        sd[t] += u;
        __syncthreads();
    }
    if (i < N_NODES) chunkscan[i] = sd[t] - v;   // exclusive within chunk
    if (t == 255) csum[blockIdx.x] = sd[255];    // chunk total
}

__global__ void k_scan2(int* __restrict__ csum, int nb) {
    __shared__ int sd[256];
    int t = threadIdx.x;
    int v = (t < nb) ? csum[t] : 0;
    sd[t] = v;
    __syncthreads();
    for (int off = 1; off < 256; off <<= 1) {
        int u = (t >= off) ? sd[t - off] : 0;
        __syncthreads();
        sd[t] += u;
        __syncthreads();
    }
    if (t < nb) csum[t] = sd[t] - v;             // exclusive scan of chunk totals
}

__global__ void k_finalize(const int* __restrict__ cnt, const int* __restrict__ chunkscan,
                           const int* __restrict__ csum, int* __restrict__ rowptr,
                           int* __restrict__ cursor, float* __restrict__ dinv) {
    int i = blockIdx.x * 256 + threadIdx.x;
    if (i < N_NODES) {
        int r = chunkscan[i] + csum[i >> 8];
        rowptr[i] = r;
        cursor[i] = r;
        dinv[i] = rsqrtf((float)cnt[i] + 1.0f);  // +1 self-loop
    }
    if (i == 0) rowptr[N_NODES] = N_EDGES;
}

// dst-bucket-partitioned CSR scatter: block b handles dst in [6250*(b&7), +6250),
// so cursor atomics + esrc writes stay in that XCD's L2 (bid%8 -> XCD round-robin).
__global__ void k_scatter(const int* __restrict__ ei, int* __restrict__ cursor,
                          int* __restrict__ esrc) {
    const int p = blockIdx.x & 7;
    int e = (blockIdx.x >> 3) * 256 + threadIdx.x;   // grid/8*256 == N_EDGES exactly
    const int lo = p * DST_BUCKET, hi = lo + DST_BUCKET;
    int dt = __builtin_nontemporal_load(&ei[N_EDGES + e]);
    if (dt >= lo && dt < hi) {
        int s = ei[e];
        int pos = atomicAdd(&cursor[dt], 1);
        esrc[pos] = s;
    }
}

// ---------- dense transform via MFMA: H' = fp16( (X @ W) * dinv[row] ) ----------
// 256 threads = 4 waves, 64 rows/block (wave w: rows base+16w..+15).
// W staged transposed fp16 in LDS once; all 32 B-frags (8 col-tiles x 4 k-steps)
// live in VGPRs. A-frags loaded straight from global (16B/lane). C goes out
// through LDS (reusing the W buffer) for coalesced fp16 row stores.
// Frag maps: A lane l -> row=l&15, k=(l>>4)*8+j ; B lane l -> col=l&15, same k;
// C/D lane l -> col=l&15, row=(l>>4)*4+reg (verified m89 layout).

template <typename XT>
__global__ __launch_bounds__(256) void k_gemm(const XT* __restrict__ X,
                                              const float* __restrict__ W,
                                              const float* __restrict__ dinv,
                                              _Float16* __restrict__ H) {
    __shared__ __align__(16) _Float16 WT[128 * WT_LD];   // 34 KiB; reused for C staging

    const int tid  = threadIdx.x;
    const int base = blockIdx.x * 64;
    const int w    = tid >> 6;          // wave 0..3
    const int lane = tid & 63;
    const int c    = lane & 15;         // row (A) / col (B,C)
    const int g    = lane >> 4;         // k-group

    // stage W^T as fp16: WT[col][k]
    for (int idx = tid; idx < 128 * 128; idx += 256) {
        int k = idx >> 7, cc = idx & 127;
        WT[cc * WT_LD + k] = (_Float16)W[idx];
    }
    __syncthreads();

    // B-frags to registers: bf[n][t] = W[k = t*32+g*8 .. +8][col = n*16+c]
    half8 bf[8][4];
#pragma unroll
    for (int n = 0; n < 8; ++n)
#pragma unroll
        for (int t = 0; t < 4; ++t)
            bf[n][t] = *(const half8*)&WT[(n * 16 + c) * WT_LD + t * 32 + g * 8];
    __syncthreads();                     // all reads of WT done before C reuses it

    // A-frags straight from global
    int rowA = base + w * 16 + c;
    if (rowA >= N_NODES) rowA = N_NODES - 1;       // clamp; tail rows never stored
    half8 af[4];
#pragma unroll
    for (int t = 0; t < 4; ++t) {
        if constexpr (sizeof(XT) == 2)
            af[t] = *(const half8*)(X + (size_t)rowA * D + t * 32 + g * 8);
        else
            af[t] = cvt8((const float*)X + (size_t)rowA * D + t * 32 + g * 8);
    }

    f32x4 acc[8];
#pragma unroll
    for (int n = 0; n < 8; ++n) acc[n] = (f32x4)0.f;
#pragma unroll
    for (int t = 0; t < 4; ++t)
#pragma unroll
        for (int n = 0; n < 8; ++n)
            acc[n] = __builtin_amdgcn_mfma_f32_16x16x32_f16(af[t], bf[n][t], acc[n], 0, 0, 0);

    // epilogue: scale by dinv, drop to fp16 via LDS for coalesced stores
    float dv[4];
#pragma unroll
    for (int j = 0; j < 4; ++j) {
        int rr = base + w * 16 + g * 4 + j;
        dv[j] = dinv[rr < N_NODES ? rr : N_NODES - 1];
    }
#pragma unroll
    for (int n = 0; n < 8; ++n)
#pragma unroll
        for (int j = 0; j < 4; ++j)
            WT[(w * 16 + g * 4 + j) * WT_LD + n * 16 + c] = (_Float16)(acc[n][j] * dv[j]);
    __syncthreads();

    for (int idx = tid; idx < 64 * 16; idx += 256) {   // 64 rows x 16 chunks of 8 fp16
        int r = idx >> 4, ch = idx & 15;
        int gr = base + r;
        if (gr < N_NODES)
            *(half8*)(H + (size_t)gr * D + ch * 8) = *(const half8*)&WT[r * WT_LD + ch * 8];
    }
}

// ---------- aggregation: out[n] = dinv[n]*(h'[n] + sum_e h'[src]) + b ----------
// 32 lanes per node (f16x4 = 8 B/lane, 256 B/row = 4 cache lines per edge).
// Output dtype templated: fp16 between layers, f32 for the final output.

template <int RELU, typename OT>
__global__ __launch_bounds__(256) void k_agg(const _Float16* __restrict__ Hs,
                                             const int* __restrict__ esrc,
                                             const int* __restrict__ rowptr,
                                             const float* __restrict__ dinv,
                                             const float* __restrict__ bias,
                                             OT* __restrict__ OUT) {
    int node = blockIdx.x * 8 + (threadIdx.x >> 5);
    int lane = threadIdx.x & 31;
    const f16x4* Hv = (const f16x4*)Hs;

    float di = dinv[node];
    f32x4 acc = cvt4(Hv[(size_t)node * 32 + lane]);   // h'[n] (self-loop term)

    int s = rowptr[node], e = rowptr[node + 1];
    for (int off = s; off < e; off += 32) {
        int n = e - off;
        if (n > 32) n = 32;
        int idx  = off + (lane < n ? lane : n - 1);   // clamp: no OOB reads
        int eidx = __builtin_nontemporal_load(&esrc[idx]);
        int j = 0;
        for (; j + 3 < n; j += 4) {
            int s0 = __shfl(eidx, j, 32);
            int s1 = __shfl(eidx, j + 1, 32);
            int s2 = __shfl(eidx, j + 2, 32);
            int s3 = __shfl(eidx, j + 3, 32);
            f16x4 v0 = Hv[(size_t)s0 * 32 + lane];
            f16x4 v1 = Hv[(size_t)s1 * 32 + lane];
            f16x4 v2 = Hv[(size_t)s2 * 32 + lane];
            f16x4 v3 = Hv[(size_t)s3 * 32 + lane];
            acc += (cvt4(v0) + cvt4(v1)) + (cvt4(v2) + cvt4(v3));
        }
        for (; j < n; ++j) {
            int s0 = __shfl(eidx, j, 32);
            acc += cvt4(Hv[(size_t)s0 * 32 + lane]);
        }
    }

    f32x4 b = ((const f32x4*)bias)[lane];
    f32x4 r = acc * di + b;
    if (RELU) {
        r.x = fmaxf(r.x, 0.f);
        r.y = fmaxf(r.y, 0.f);
        r.z = fmaxf(r.z, 0.f);
        r.w = fmaxf(r.w, 0.f);
    }
    if constexpr (sizeof(OT) == 2) {
        f16x4 o;
        o.x = (_Float16)r.x; o.y = (_Float16)r.y;
        o.z = (_Float16)r.z; o.w = (_Float16)r.w;
        __builtin_nontemporal_store(o, (f16x4*)OUT + (size_t)node * 32 + lane);
    } else {
        __builtin_nontemporal_store(r, (f32x4*)OUT + (size_t)node * 32 + lane);
    }
}

// ---------- launch ----------

extern "C" void kernel_launch(void* const* d_in, const int* in_sizes, int n_in,
                              void* d_out, int out_size, void* d_ws, size_t ws_size,
                              hipStream_t stream) {
    const float* x  = (const float*)d_in[0];
    const int*   ei = (const int*)d_in[1];
    const float* W1 = (const float*)d_in[2];
    const float* b1 = (const float*)d_in[3];
    const float* W2 = (const float*)d_in[4];
    const float* b2 = (const float*)d_in[5];
    float* out = (float*)d_out;

    // ws layout (elements, 4B each; chunks padded to keep 16B alignment)
    int*      cnt       = (int*)d_ws;               // 50000
    int*      chunkscan = cnt + 50048;              // 50000
    int*      csum      = chunkscan + 50048;        // 256
    int*      rowptr    = csum + 256;               // 50001
    int*      cursor    = rowptr + 50048;           // 50000
    float*    dinv      = (float*)(cursor + 50048); // 50000
    int*      esrc      = (int*)(dinv + 50048);     // 800000
    _Float16* h1        = (_Float16*)(esrc + 800000);   // 6.4M halves (12.8 MB)
    _Float16* ag16      = h1 + 6400000;                 // 6.4M halves (12.8 MB)
    _Float16* h2        = ag16 + 6400000;               // 6.4M halves (12.8 MB)

    const int TB = 256;
    const int gbN = (N_NODES + TB - 1) / TB;     // 196
    const int gbE = (N_EDGES + TB - 1) / TB;     // 3125
    const int gbG = (N_NODES + 63) / 64;         // 782 gemm blocks

    // graph build (shared by both layers)
    k_zero<<<gbN, TB, 0, stream>>>(cnt, N_NODES);
    k_hist<<<gbE, TB, 0, stream>>>(ei, cnt);
    k_scan1<<<NCHUNK, TB, 0, stream>>>(cnt, chunkscan, csum);
    k_scan2<<<1, TB, 0, stream>>>(csum, NCHUNK);
    k_finalize<<<gbN, TB, 0, stream>>>(cnt, chunkscan, csum, rowptr, cursor, dinv);
    k_scatter<<<8 * gbE, TB, 0, stream>>>(ei, cursor, esrc);

    // layer 1
    k_gemm<float><<<gbG, TB, 0, stream>>>(x, W1, dinv, h1);
    k_agg<1, _Float16><<<N_NODES / 8, TB, 0, stream>>>(h1, esrc, rowptr, dinv, b1, ag16);
    // layer 2
    k_gemm<_Float16><<<gbG, TB, 0, stream>>>(ag16, W2, dinv, h2);
    k_agg<0, float><<<N_NODES / 8, TB, 0, stream>>>(h2, esrc, rowptr, dinv, b2, out);
}

// Round 7
// 124.960 us; speedup vs baseline: 2.5351x; 1.4256x over previous
//
#include <hip/hip_runtime.h>

#define N_NODES 50000
#define N_EDGES 800000
#define D 128
#define NBUCK 196             // ceil(50000/256) dst buckets of 256 nodes
#define CAP 8192              // edges capacity per bucket region (mean 4096, sd 64)
#define WT_LD 136             // 128 + 8 fp16 pad (272B row stride, bank-spread)

typedef float    f32x4 __attribute__((ext_vector_type(4)));
typedef _Float16 f16x4 __attribute__((ext_vector_type(4)));
typedef _Float16 half8 __attribute__((ext_vector_type(8)));

__device__ inline f32x4 cvt4(f16x4 h) {
    f32x4 r;
    r.x = (float)h.x; r.y = (float)h.y; r.z = (float)h.z; r.w = (float)h.w;
    return r;
}

__device__ inline half8 cvt8(const float* __restrict__ p) {
    f32x4 a = *(const f32x4*)p;
    f32x4 b = *(const f32x4*)(p + 4);
    half8 r;
    r[0] = (_Float16)a.x; r[1] = (_Float16)a.y; r[2] = (_Float16)a.z; r[3] = (_Float16)a.w;
    r[4] = (_Float16)b.x; r[5] = (_Float16)b.y; r[6] = (_Float16)b.z; r[7] = (_Float16)b.w;
    return r;
}

// ---------- graph build: two-phase LDS counting sort ----------

__global__ void k_zero(int* __restrict__ p, int n) {
    int i = blockIdx.x * blockDim.x + threadIdx.x;
    if (i < n) p[i] = 0;
}

// Phase A: bucket edges by dst>>8 into fixed-capacity regions.
// Record = src | (dstlocal<<16); src < 50000 < 2^16, dstlocal < 256.
__global__ __launch_bounds__(256) void k_bucket(const int* __restrict__ ei,
                                                int* __restrict__ gcur,
                                                int* __restrict__ pk) {
    __shared__ int lcnt[NBUCK];
    __shared__ int lbase[NBUCK];
    const int t = threadIdx.x;
    for (int i = t; i < NBUCK; i += 256) lcnt[i] = 0;
    __syncthreads();

    const int base = blockIdx.x * 2048;
    int  vals[8], bks[8], rks[8];
    bool ok[8];
#pragma unroll
    for (int u = 0; u < 8; ++u) {
        int e = base + u * 256 + t;
        ok[u] = (e < N_EDGES);
        if (ok[u]) {
            int s = ei[e];
            int d = ei[N_EDGES + e];
            bks[u]  = d >> 8;
            vals[u] = s | ((d & 255) << 16);
            rks[u]  = atomicAdd(&lcnt[bks[u]], 1);
        }
    }
    __syncthreads();
    for (int i = t; i < NBUCK; i += 256)
        lbase[i] = lcnt[i] ? atomicAdd(&gcur[i], lcnt[i]) : 0;
    __syncthreads();
#pragma unroll
    for (int u = 0; u < 8; ++u)
        if (ok[u])
            pk[bks[u] * CAP + lbase[bks[u]] + rks[u]] = vals[u];
}

// Phase B: one block per bucket. LDS hist over 256 dsts -> scan -> rowstart/
// rowcnt/dinv; stable-place esrc in LDS staging, write out coalesced.
__global__ __launch_bounds__(256) void k_csr(const int* __restrict__ gcur,
                                             const int* __restrict__ pk,
                                             int* __restrict__ rowstart,
                                             int* __restrict__ rowcnt,
                                             float* __restrict__ dinv,
                                             int* __restrict__ esrc) {
    __shared__ int hcnt[256];
    __shared__ int sbase[256];
    __shared__ int lcur[256];
    __shared__ int sd[256];
    __shared__ int lesrc[CAP];

    const int b  = blockIdx.x;
    const int t  = threadIdx.x;
    const int RB = b * CAP;
    const int nb = gcur[b];

    hcnt[t] = 0;
    lcur[t] = 0;
    __syncthreads();
    for (int i = t; i < nb; i += 256) {
        int dl = (pk[RB + i] >> 16) & 255;
        atomicAdd(&hcnt[dl], 1);
    }
    __syncthreads();

    // exclusive scan of hcnt
    int v = hcnt[t];
    sd[t] = v;
    __syncthreads();
    for (int off = 1; off < 256; off <<= 1) {
        int u = (t >= off) ? sd[t - off] : 0;
        __syncthreads();
        sd[t] += u;
        __syncthreads();
    }
    sbase[t] = sd[t] - v;
    __syncthreads();

    int g = b * 256 + t;
    if (g < N_NODES) {
        rowstart[g] = RB + sbase[t];
        rowcnt[g]   = v;
        dinv[g]     = rsqrtf((float)v + 1.0f);   // +1 self-loop
    }

    for (int i = t; i < nb; i += 256) {
        int val = pk[RB + i];
        int dl  = (val >> 16) & 255;
        int r   = atomicAdd(&lcur[dl], 1);
        lesrc[sbase[dl] + r] = val & 0xFFFF;
    }
    __syncthreads();
    for (int i = t; i < nb; i += 256)
        esrc[RB + i] = lesrc[i];
}

// ---------- dense transform via MFMA: H' = fp16( (X @ W) * dinv[row] ) ----------
// 256 threads = 4 waves, 64 rows/block (wave w: rows base+16w..+15).
// W staged transposed fp16 in LDS once; all 32 B-frags (8 col-tiles x 4 k-steps)
// live in VGPRs. A-frags loaded straight from global (16B/lane). C goes out
// through LDS (reusing the W buffer) for coalesced fp16 row stores.
// Frag maps: A lane l -> row=l&15, k=(l>>4)*8+j ; B lane l -> col=l&15, same k;
// C/D lane l -> col=l&15, row=(l>>4)*4+reg (verified m89 layout).

template <typename XT>
__global__ __launch_bounds__(256) void k_gemm(const XT* __restrict__ X,
                                              const float* __restrict__ W,
                                              const float* __restrict__ dinv,
                                              _Float16* __restrict__ H) {
    __shared__ __align__(16) _Float16 WT[128 * WT_LD];   // 34 KiB; reused for C staging

    const int tid  = threadIdx.x;
    const int base = blockIdx.x * 64;
    const int w    = tid >> 6;          // wave 0..3
    const int lane = tid & 63;
    const int c    = lane & 15;         // row (A) / col (B,C)
    const int g    = lane >> 4;         // k-group

    // stage W^T as fp16: WT[col][k]
    for (int idx = tid; idx < 128 * 128; idx += 256) {
        int k = idx >> 7, cc = idx & 127;
        WT[cc * WT_LD + k] = (_Float16)W[idx];
    }
    __syncthreads();

    // B-frags to registers: bf[n][t] = W[k = t*32+g*8 .. +8][col = n*16+c]
    half8 bf[8][4];
#pragma unroll
    for (int n = 0; n < 8; ++n)
#pragma unroll
        for (int t = 0; t < 4; ++t)
            bf[n][t] = *(const half8*)&WT[(n * 16 + c) * WT_LD + t * 32 + g * 8];
    __syncthreads();                     // all reads of WT done before C reuses it

    // A-frags straight from global
    int rowA = base + w * 16 + c;
    if (rowA >= N_NODES) rowA = N_NODES - 1;       // clamp; tail rows never stored
    half8 af[4];
#pragma unroll
    for (int t = 0; t < 4; ++t) {
        if constexpr (sizeof(XT) == 2)
            af[t] = *(const half8*)(X + (size_t)rowA * D + t * 32 + g * 8);
        else
            af[t] = cvt8((const float*)X + (size_t)rowA * D + t * 32 + g * 8);
    }

    f32x4 acc[8];
#pragma unroll
    for (int n = 0; n < 8; ++n) acc[n] = (f32x4)0.f;
#pragma unroll
    for (int t = 0; t < 4; ++t)
#pragma unroll
        for (int n = 0; n < 8; ++n)
            acc[n] = __builtin_amdgcn_mfma_f32_16x16x32_f16(af[t], bf[n][t], acc[n], 0, 0, 0);

    // epilogue: scale by dinv, drop to fp16 via LDS for coalesced stores
    float dv[4];
#pragma unroll
    for (int j = 0; j < 4; ++j) {
        int rr = base + w * 16 + g * 4 + j;
        dv[j] = dinv[rr < N_NODES ? rr : N_NODES - 1];
    }
#pragma unroll
    for (int n = 0; n < 8; ++n)
#pragma unroll
        for (int j = 0; j < 4; ++j)
            WT[(w * 16 + g * 4 + j) * WT_LD + n * 16 + c] = (_Float16)(acc[n][j] * dv[j]);
    __syncthreads();

    for (int idx = tid; idx < 64 * 16; idx += 256) {   // 64 rows x 16 chunks of 8 fp16
        int r = idx >> 4, ch = idx & 15;
        int gr = base + r;
        if (gr < N_NODES)
            *(half8*)(H + (size_t)gr * D + ch * 8) = *(const half8*)&WT[r * WT_LD + ch * 8];
    }
}

// ---------- aggregation: out[n] = dinv[n]*(h'[n] + sum_e h'[src]) + b ----------
// 32 lanes per node (f16x4 = 8 B/lane, 256 B/row = 4 cache lines per edge).
// Coalesced 32-wide edge-index load + __shfl broadcast; 8 row-gathers in flight.

template <int RELU, typename OT>
__global__ __launch_bounds__(256) void k_agg(const _Float16* __restrict__ Hs,
                                             const int* __restrict__ rowstart,
                                             const int* __restrict__ rowcnt,
                                             const int* __restrict__ esrc,
                                             const float* __restrict__ dinv,
                                             const float* __restrict__ bias,
                                             OT* __restrict__ OUT) {
    int node = blockIdx.x * 8 + (threadIdx.x >> 5);
    int lane = threadIdx.x & 31;
    const f16x4* Hv = (const f16x4*)Hs;

    float di = dinv[node];
    f32x4 acc = cvt4(Hv[(size_t)node * 32 + lane]);   // h'[n] (self-loop term)

    int s   = __builtin_nontemporal_load(&rowstart[node]);
    int cnt = __builtin_nontemporal_load(&rowcnt[node]);
    int e   = s + cnt;
    for (int off = s; off < e; off += 32) {
        int n = e - off;
        if (n > 32) n = 32;
        int idx  = off + (lane < n ? lane : n - 1);   // clamp: no OOB reads
        int eidx = __builtin_nontemporal_load(&esrc[idx]);
        int j = 0;
        for (; j + 7 < n; j += 8) {
            int s0 = __shfl(eidx, j, 32);
            int s1 = __shfl(eidx, j + 1, 32);
            int s2 = __shfl(eidx, j + 2, 32);
            int s3 = __shfl(eidx, j + 3, 32);
            int s4 = __shfl(eidx, j + 4, 32);
            int s5 = __shfl(eidx, j + 5, 32);
            int s6 = __shfl(eidx, j + 6, 32);
            int s7 = __shfl(eidx, j + 7, 32);
            f16x4 v0 = Hv[(size_t)s0 * 32 + lane];
            f16x4 v1 = Hv[(size_t)s1 * 32 + lane];
            f16x4 v2 = Hv[(size_t)s2 * 32 + lane];
            f16x4 v3 = Hv[(size_t)s3 * 32 + lane];
            f16x4 v4 = Hv[(size_t)s4 * 32 + lane];
            f16x4 v5 = Hv[(size_t)s5 * 32 + lane];
            f16x4 v6 = Hv[(size_t)s6 * 32 + lane];
            f16x4 v7 = Hv[(size_t)s7 * 32 + lane];
            acc += ((cvt4(v0) + cvt4(v1)) + (cvt4(v2) + cvt4(v3)))
                 + ((cvt4(v4) + cvt4(v5)) + (cvt4(v6) + cvt4(v7)));
        }
        for (; j + 3 < n; j += 4) {
            int s0 = __shfl(eidx, j, 32);
            int s1 = __shfl(eidx, j + 1, 32);
            int s2 = __shfl(eidx, j + 2, 32);
            int s3 = __shfl(eidx, j + 3, 32);
            f16x4 v0 = Hv[(size_t)s0 * 32 + lane];
            f16x4 v1 = Hv[(size_t)s1 * 32 + lane];
            f16x4 v2 = Hv[(size_t)s2 * 32 + lane];
            f16x4 v3 = Hv[(size_t)s3 * 32 + lane];
            acc += (cvt4(v0) + cvt4(v1)) + (cvt4(v2) + cvt4(v3));
        }
        for (; j < n; ++j) {
            int s0 = __shfl(eidx, j, 32);
            acc += cvt4(Hv[(size_t)s0 * 32 + lane]);
        }
    }

    f32x4 b = ((const f32x4*)bias)[lane];
    f32x4 r = acc * di + b;
    if (RELU) {
        r.x = fmaxf(r.x, 0.f);
        r.y = fmaxf(r.y, 0.f);
        r.z = fmaxf(r.z, 0.f);
        r.w = fmaxf(r.w, 0.f);
    }
    if constexpr (sizeof(OT) == 2) {
        f16x4 o;
        o.x = (_Float16)r.x; o.y = (_Float16)r.y;
        o.z = (_Float16)r.z; o.w = (_Float16)r.w;
        __builtin_nontemporal_store(o, (f16x4*)OUT + (size_t)node * 32 + lane);
    } else {
        __builtin_nontemporal_store(r, (f32x4*)OUT + (size_t)node * 32 + lane);
    }
}

// ---------- launch ----------

extern "C" void kernel_launch(void* const* d_in, const int* in_sizes, int n_in,
                              void* d_out, int out_size, void* d_ws, size_t ws_size,
                              hipStream_t stream) {
    const float* x  = (const float*)d_in[0];
    const int*   ei = (const int*)d_in[1];
    const float* W1 = (const float*)d_in[2];
    const float* b1 = (const float*)d_in[3];
    const float* W2 = (const float*)d_in[4];
    const float* b2 = (const float*)d_in[5];
    float* out = (float*)d_out;

    // ws layout (4B units; regions padded for 16B alignment)
    int*      gcur     = (int*)d_ws;                    // 256 (196 used)
    int*      rowstart = gcur + 256;                    // 50048
    int*      rowcnt   = rowstart + 50048;              // 50048
    float*    dinv     = (float*)(rowcnt + 50048);      // 50048
    int*      pk       = (int*)(dinv + 50048);          // 196*8192 = 1,605,632
    int*      esrc     = pk + NBUCK * CAP;              // 1,605,632
    _Float16* h1       = (_Float16*)(esrc + NBUCK * CAP); // 6.4M halves (12.8 MB)
    _Float16* ag16     = h1 + 6400000;                  // 6.4M halves
    _Float16* h2       = ag16 + 6400000;                // 6.4M halves

    const int TB  = 256;
    const int gbB = (N_EDGES + 2047) / 2048;     // 391 bucket blocks
    const int gbG = (N_NODES + 63) / 64;         // 782 gemm blocks

    // graph build (shared by both layers): zero cursors -> bucket -> CSR
    k_zero<<<1, TB, 0, stream>>>(gcur, NBUCK);
    k_bucket<<<gbB, TB, 0, stream>>>(ei, gcur, pk);
    k_csr<<<NBUCK, TB, 0, stream>>>(gcur, pk, rowstart, rowcnt, dinv, esrc);

    // layer 1
    k_gemm<float><<<gbG, TB, 0, stream>>>(x, W1, dinv, h1);
    k_agg<1, _Float16><<<N_NODES / 8, TB, 0, stream>>>(h1, rowstart, rowcnt, esrc, dinv, b1, ag16);
    // layer 2
    k_gemm<_Float16><<<gbG, TB, 0, stream>>>(ag16, W2, dinv, h2);
    k_agg<0, float><<<N_NODES / 8, TB, 0, stream>>>(h2, rowstart, rowcnt, esrc, dinv, b2, out);
}